// Round 11
// baseline (159.247 us; speedup 1.0000x reference)
//
#include <hip/hip_runtime.h>
#include <hip/hip_bf16.h>

#define N_NODES 2048
#define EMB 768
#define NH 8
#define DH 96
#define ALPHA 0.2f
#define SCALE 0.10206207261596575f  // 96^-0.5
#define NGMAX 192
#define WSZ (EMB * EMB)

typedef __bf16 bf16x8 __attribute__((ext_vector_type(8)));
typedef float f32x4 __attribute__((ext_vector_type(4)));
typedef __attribute__((address_space(3))) unsigned int lds_u32;
typedef __attribute__((address_space(1))) const unsigned int glb_u32;

union pack4 { ushort4 u; __hip_bfloat16 h[4]; };

// ---------------------------------------------------------------- prep: concat-cast e + cast 3 weights + zero cnt
__global__ __launch_bounds__(256) void prep_kernel(
    const float* __restrict__ eh, const float* __restrict__ er, const float* __restrict__ et,
    const float* __restrict__ W0, const float* __restrict__ W1, const float* __restrict__ W2,
    __hip_bfloat16* __restrict__ e, __hip_bfloat16* __restrict__ o0,
    __hip_bfloat16* __restrict__ o1, __hip_bfloat16* __restrict__ o2, int* __restrict__ cnt)
{
    const int b = blockIdx.x;
    const int gtid = b * 256 + threadIdx.x;
    if (gtid < 32) cnt[gtid] = 0;
    const float* src;
    __hip_bfloat16* dst;
    if (b < 1536) {                       // e = concat(eh,er,et)
        int idx = gtid * 4;
        int i = idx / EMB, c = idx % EMB;
        if (c < 256)      src = eh + i * 256 + c;
        else if (c < 512) src = er + i * 256 + (c - 256);
        else              src = et + i * 256 + (c - 512);
        dst = e + (size_t)i * EMB + c;
    } else {                              // three 768x768 weights
        int idx = (gtid - 1536 * 256) * 4;
        if (idx < WSZ)          { src = W0 + idx;           dst = o0 + idx; }
        else if (idx < 2 * WSZ) { src = W1 + idx - WSZ;     dst = o1 + idx - WSZ; }
        else                    { src = W2 + idx - 2 * WSZ; dst = o2 + idx - 2 * WSZ; }
    }
    float4 v = *reinterpret_cast<const float4*>(src);
    pack4 p;
    p.h[0] = __float2bfloat16(v.x);
    p.h[1] = __float2bfloat16(v.y);
    p.h[2] = __float2bfloat16(v.z);
    p.h[3] = __float2bfloat16(v.w);
    *reinterpret_cast<ushort4*>(dst) = p.u;
}

// ---------------------------------------------------------------- 128x128-tile MFMA GEMM (m97-style 4x4 wave frags)
// C = A1@B1^T [+ A2@B2^T] [+ bias1+bias2], row-major ld=EMB, M=2048, N=768.
// Grid (6,16) = 96 blocks. 4 waves in 2x2, wave tile 64x64 = 4x4 of 16x16x32 MFMA
// -> 8 ds_read_b128 per K=32 slab feed 16 MFMAs = 32 flop/LDS-byte (2x R8).
// BK=64 double-buffer = exactly 64 KB LDS. global_load_lds width=16;
// 16B-chunk XOR swizzle: chunk (row, cb) at slot row*8 + (cb ^ (row&7)).
__global__ __launch_bounds__(256) void gemm_kernel(
    const __hip_bfloat16* __restrict__ A1, const __hip_bfloat16* __restrict__ B1, int ns1,
    const __hip_bfloat16* __restrict__ A2, const __hip_bfloat16* __restrict__ B2, int ns2,
    const float* __restrict__ bias1, const float* __restrict__ bias2,
    float* __restrict__ Cf)
{
    __shared__ __attribute__((aligned(16))) __hip_bfloat16 smA[2][8192];  // 128 rows x 64 k
    __shared__ __attribute__((aligned(16))) __hip_bfloat16 smB[2][8192];

    const int t = threadIdx.x;
    const int lane = t & 63, wave = t >> 6;
    const int wm = wave >> 1, wn = wave & 1;
    const int l15 = lane & 15, quad = lane >> 4;
    const int bm = blockIdx.y * 128, bn = blockIdx.x * 128;
    const int NS = ns1 + ns2;

    f32x4 acc[4][4];
#pragma unroll
    for (int fr = 0; fr < 4; fr++)
#pragma unroll
        for (int fc = 0; fc < 4; fc++) acc[fr][fc] = (f32x4){0.f, 0.f, 0.f, 0.f};

    auto stage = [&](const __hip_bfloat16* A, const __hip_bfloat16* B, int k0, int bi) {
#pragma unroll
        for (int i = 0; i < 4; i++) {               // A: 128 rows x 8 chunks = 1024
            int L = t + i * 256, row = L >> 3, cb = (L & 7) ^ (row & 7);
            __builtin_amdgcn_global_load_lds(
                (glb_u32*)(A + (size_t)(bm + row) * EMB + k0 + cb * 8),
                (lds_u32*)(&smA[bi][0] + L * 8), 16, 0, 0);
        }
#pragma unroll
        for (int i = 0; i < 4; i++) {               // B: 128 rows x 8 chunks = 1024
            int L = t + i * 256, row = L >> 3, cb = (L & 7) ^ (row & 7);
            __builtin_amdgcn_global_load_lds(
                (glb_u32*)(B + (size_t)(bn + row) * EMB + k0 + cb * 8),
                (lds_u32*)(&smB[bi][0] + L * 8), 16, 0, 0);
        }
    };

    stage(A1, B1, 0, 0);

    for (int s = 0; s < NS; s++) {
        __syncthreads();                  // vmcnt drain: stage s resident
        if (s + 1 < NS) {
            const int sn = s + 1;
            const __hip_bfloat16* As = (sn < ns1) ? A1 : A2;
            const __hip_bfloat16* Bs = (sn < ns1) ? B1 : B2;
            stage(As, Bs, ((sn < ns1) ? sn : sn - ns1) * 64, sn & 1);
        }
        const __hip_bfloat16* At = smA[s & 1];
        const __hip_bfloat16* Bt = smB[s & 1];
#pragma unroll
        for (int ks = 0; ks < 2; ks++) {
            const int cq = ks * 4 + quad;
            bf16x8 a[4], b[4];
#pragma unroll
            for (int fr = 0; fr < 4; fr++) {
                const int r = wm * 64 + fr * 16 + l15;
                a[fr] = *(const bf16x8*)(At + (size_t)((r << 3) + (cq ^ (r & 7))) * 8);
            }
#pragma unroll
            for (int fc = 0; fc < 4; fc++) {
                const int r = wn * 64 + fc * 16 + l15;
                b[fc] = *(const bf16x8*)(Bt + (size_t)((r << 3) + (cq ^ (r & 7))) * 8);
            }
#pragma unroll
            for (int fr = 0; fr < 4; fr++)
#pragma unroll
                for (int fc = 0; fc < 4; fc++)
                    acc[fr][fc] = __builtin_amdgcn_mfma_f32_16x16x32_bf16(a[fr], b[fc], acc[fr][fc], 0, 0, 0);
        }
    }

#pragma unroll
    for (int fc = 0; fc < 4; fc++) {
        const int col = bn + wn * 64 + fc * 16 + l15;
        const float bv = (bias1 != nullptr) ? (bias1[col] + bias2[col]) : 0.f;
#pragma unroll
        for (int fr = 0; fr < 4; fr++) {
            const int r0 = bm + wm * 64 + fr * 16 + quad * 4;
#pragma unroll
            for (int r = 0; r < 4; r++)
                Cf[(size_t)(r0 + r) * EMB + col] = acc[fr][fc][r] + bv;
        }
    }
}

// ---------------------------------------------------------------- s1/s2 + group lists (R8-proven)
__global__ __launch_bounds__(256) void s12g_kernel(
    const float* __restrict__ Wh, const float* __restrict__ a,
    float* __restrict__ s1, float* __restrict__ s2,
    const int* __restrict__ h_id, int* __restrict__ cnt, int* __restrict__ lists)
{
    int gid = blockIdx.x * 256 + threadIdx.x;  // [0, N*NH)
    if (gid < N_NODES) {
        int g = h_id[gid];
        int p = atomicAdd(&cnt[g], 1);
        lists[g * N_NODES + p] = gid;
    }
    int i = gid >> 3, h = gid & 7;
    const float* wr = Wh + (size_t)i * EMB + h * DH;
    float acc1 = 0.f, acc2 = 0.f;
    for (int d = 0; d < DH; d++) {
        float w = wr[d];
        acc1 += w * a[d];
        acc2 += w * a[DH + d];
    }
    s1[gid] = acc1;
    s2[gid] = acc2;
}

// ---------------------------------------------------------------- attention: block per (group, head, col-half) (R8-proven)
__global__ __launch_bounds__(256) void attn_kernel(
    const float* __restrict__ Wh, const float* __restrict__ s1, const float* __restrict__ s2,
    const int* __restrict__ cnt, const int* __restrict__ lists,
    __hip_bfloat16* __restrict__ out)
{
    const int g  = blockIdx.x & 31;
    const int h  = (blockIdx.x >> 5) & 7;
    const int dh = blockIdx.x >> 8;          // 0/1 -> cols [dh*48, dh*48+48)
    const int t  = threadIdx.x;

    __shared__ int   jb[NGMAX];
    __shared__ int   qg[NGMAX];
    __shared__ float s2g[NGMAX];
    __shared__ float s1g[NGMAX][9];          // pad 9: stride-8 would 16-way conflict
    __shared__ float Whg[NGMAX][48];

    const int ng = min(cnt[g], NGMAX);
    const int* gl = lists + g * N_NODES;

    for (int j = t; j < ng; j += 256) {
        int node = gl[j];
        jb[j]  = node;
        qg[j]  = node >> 8;
        s2g[j] = s2[node * 8 + h];
        float4 v0 = *reinterpret_cast<const float4*>(s1 + node * 8);
        float4 v1 = *reinterpret_cast<const float4*>(s1 + node * 8 + 4);
        s1g[j][0] = v0.x; s1g[j][1] = v0.y; s1g[j][2] = v0.z; s1g[j][3] = v0.w;
        s1g[j][4] = v1.x; s1g[j][5] = v1.y; s1g[j][6] = v1.z; s1g[j][7] = v1.w;
    }
    __syncthreads();
    for (int idx = t; idx < ng * 12; idx += 256) {
        int jc = idx / 12, dq = idx % 12;
        float4 v = *reinterpret_cast<const float4*>(
            Wh + (size_t)jb[jc] * EMB + h * DH + dh * 48 + dq * 4);
        *reinterpret_cast<float4*>(&Whg[jc][dq * 4]) = v;
    }
    __syncthreads();

    if (t < ng) {
        float m = -1e30f;
        for (int j = 0; j < ng; j++) {
            float x = s1g[t][qg[j]] + s2g[j];
            float ev = (x >= 0.f ? x : ALPHA * x) * SCALE;
            m = fmaxf(m, ev);
        }
        float S = 0.f;
        for (int j = 0; j < ng; j++) {
            float x = s1g[t][qg[j]] + s2g[j];
            float ev = (x >= 0.f ? x : ALPHA * x) * SCALE;
            S += __expf(ev - m);
        }
        const float ri = 1.f / S;

        float acc[48];
#pragma unroll
        for (int d = 0; d < 48; d++) acc[d] = 0.f;
        for (int j = 0; j < ng; j++) {
            float x = s1g[t][qg[j]] + s2g[j];
            float ev = (x >= 0.f ? x : ALPHA * x) * SCALE;
            float p = __expf(ev - m) * ri;
#pragma unroll
            for (int d = 0; d < 48; d++) acc[d] += p * Whg[j][d];
        }
        __hip_bfloat16* po = out + (size_t)jb[t] * EMB + h * DH + dh * 48;
#pragma unroll
        for (int d = 0; d < 48; d += 4) {
            pack4 pk;
            pk.h[0] = __float2bfloat16(acc[d]);
            pk.h[1] = __float2bfloat16(acc[d + 1]);
            pk.h[2] = __float2bfloat16(acc[d + 2]);
            pk.h[3] = __float2bfloat16(acc[d + 3]);
            *reinterpret_cast<ushort4*>(po + d) = pk.u;
        }
    }
}

// ---------------------------------------------------------------- launch
extern "C" void kernel_launch(void* const* d_in, const int* in_sizes, int n_in,
                              void* d_out, int out_size, void* d_ws, size_t ws_size,
                              hipStream_t stream)
{
    const float* eh     = (const float*)d_in[0];
    const float* er     = (const float*)d_in[1];
    const float* et     = (const float*)d_in[2];
    const int*   h_id   = (const int*)d_in[3];
    const float* W_w    = (const float*)d_in[4];
    const float* a      = (const float*)d_in[5];
    const float* proj_w = (const float*)d_in[6];
    const float* proj_b = (const float*)d_in[7];
    const float* skip_w = (const float*)d_in[8];
    const float* skip_b = (const float*)d_in[9];
    float* out = (float*)d_out;   // reference output dtype is f32

    char* ws = (char*)d_ws;
    __hip_bfloat16* e_ws   = (__hip_bfloat16*)(ws);
    float*          Wh_ws  = (float*)(ws + 3145728);
    __hip_bfloat16* at_ws  = (__hip_bfloat16*)(ws + 9437184);
    __hip_bfloat16* Wb_ws  = (__hip_bfloat16*)(ws + 12582912);
    __hip_bfloat16* Pb_ws  = (__hip_bfloat16*)(ws + 13762560);
    __hip_bfloat16* Sb_ws  = (__hip_bfloat16*)(ws + 14942208);
    float*          s1_ws  = (float*)(ws + 16121856);
    float*          s2_ws  = (float*)(ws + 16187392);
    int*            cnt_ws = (int*)(ws + 16252928);
    int*            lst_ws = (int*)(ws + 16253056);

    prep_kernel<<<3264, 256, 0, stream>>>(eh, er, et, W_w, proj_w, skip_w,
                                          e_ws, Wb_ws, Pb_ws, Sb_ws, cnt_ws);

    // Wh = e @ W_w^T  (f32)
    gemm_kernel<<<dim3(6, 16), 256, 0, stream>>>(
        e_ws, Wb_ws, 12, nullptr, nullptr, 0, nullptr, nullptr, Wh_ws);

    s12g_kernel<<<64, 256, 0, stream>>>(Wh_ws, a, s1_ws, s2_ws, h_id, cnt_ws, lst_ws);

    attn_kernel<<<512, 256, 0, stream>>>(Wh_ws, s1_ws, s2_ws, cnt_ws, lst_ws, at_ws);

    // out = at @ proj^T + e @ skip^T + (proj_b + skip_b)  (f32)
    gemm_kernel<<<dim3(6, 16), 256, 0, stream>>>(
        at_ws, Pb_ws, 12, e_ws, Sb_ws, 12, proj_b, skip_b, out);
}